// Round 4
// baseline (607.042 us; speedup 1.0000x reference)
//
#include <hip/hip_runtime.h>

// ---------------------------------------------------------------------------
// casual MHA, MI355X. fp32 in/out, fp16 MFMA compute.
// q/k path uses 2-term fp16 split (hi+lo, 3 MFMA passes) to keep softmax
// logits (std ~1024) accurate enough that argmax-like softmax doesn't flip.
// ---------------------------------------------------------------------------

typedef __attribute__((ext_vector_type(8))) _Float16 half8;
typedef __attribute__((ext_vector_type(4))) float f32x4;

#define DEVI static __device__ __forceinline__

static constexpr int cB = 4, cS = 2048, cD = 1024, cH = 16, cDH = 64;
static constexpr int cM = cB * cS; // 8192

DEVI unsigned short h2b(_Float16 h) { union { _Float16 f; unsigned short u; } x; x.f = h; return x.u; }

DEVI void async16(const void* g, void* l) {
#if defined(__HIP_DEVICE_COMPILE__)
  __builtin_amdgcn_global_load_lds((const __attribute__((address_space(1))) unsigned int*)g,
                                   (__attribute__((address_space(3))) unsigned int*)l, 16, 0, 0);
#endif
}

// ---- split fp32 -> fp16 hi (+lo) --------------------------------------------
__global__ void split_f16_kernel(const float* __restrict__ in, unsigned short* __restrict__ hi,
                                 unsigned short* __restrict__ lo, int n) {
  int i = (blockIdx.x * blockDim.x + threadIdx.x) * 4;
  if (i >= n) return;
  float4 v = *(const float4*)(in + i);
  _Float16 h0 = (_Float16)v.x, h1 = (_Float16)v.y, h2 = (_Float16)v.z, h3 = (_Float16)v.w;
  unsigned short th[4] = {h2b(h0), h2b(h1), h2b(h2), h2b(h3)};
  *(uint2*)(hi + i) = *(const uint2*)th;
  if (lo != nullptr) {
    unsigned short tl[4] = {h2b((_Float16)(v.x - (float)h0)), h2b((_Float16)(v.y - (float)h1)),
                            h2b((_Float16)(v.z - (float)h2)), h2b((_Float16)(v.w - (float)h3))};
    *(uint2*)(lo + i) = *(const uint2*)tl;
  }
}

// ---- GEMM: C[M,N] = A[M,K] @ B[N,K]^T --------------------------------------
template <int PASSES, int OUTMODE, bool A32>
__global__ __launch_bounds__(256, 2) void gemm_bt(const void* __restrict__ Ap,
                                                  const unsigned short* __restrict__ Bh,
                                                  const unsigned short* __restrict__ Bl,
                                                  void* __restrict__ C0, void* __restrict__ C1,
                                                  int M, int N, int K) {
  __shared__ float sA32[A32 ? 128 * 32 : 1];
  __shared__ unsigned short sA16[A32 ? 1 : 128 * 32];
  __shared__ unsigned short sBh[128 * 32];
  __shared__ unsigned short sBl[(PASSES == 3) ? 128 * 32 : 1];

  const int tid = threadIdx.x, lane = tid & 63, wave = tid >> 6;
  const int wm = wave >> 1, wn = wave & 1;
  const int nb = N >> 7;
  const int bm = blockIdx.x / nb, bn = blockIdx.x % nb;
  const long r0 = (long)bm * 128, c0 = (long)bn * 128;
  const int quad = lane >> 4, cl = lane & 15;

  f32x4 acc[4][4];
#pragma unroll
  for (int mt = 0; mt < 4; ++mt)
#pragma unroll
    for (int nt = 0; nt < 4; ++nt) acc[mt][nt] = f32x4{0.f, 0.f, 0.f, 0.f};

  const int lrow8 = lane >> 3, lg8 = lane & 7;
  const int lrow16 = lane >> 2, lg4 = lane & 3;

  const float* A32p = (const float*)Ap;
  const unsigned short* A16p = (const unsigned short*)Ap;

  for (int k0 = 0; k0 < K; k0 += 32) {
    __syncthreads();
    if constexpr (A32) {
#pragma unroll
      for (int c = 0; c < 4; ++c) {
        int cc = wave * 4 + c;
        int r = cc * 8 + lrow8;
        const float* g = A32p + (r0 + r) * (long)K + k0 + ((lg8 ^ lrow8) * 4);
        async16(g, sA32 + cc * 256);
      }
    } else {
#pragma unroll
      for (int c = 0; c < 2; ++c) {
        int cc = wave * 2 + c;
        int r = cc * 16 + lrow16;
        const unsigned short* g =
            A16p + (r0 + r) * (long)K + k0 + ((lg4 ^ ((lrow16 >> 1) & 3)) * 8);
        async16(g, sA16 + cc * 512);
      }
    }
#pragma unroll
    for (int c = 0; c < 2; ++c) {
      int cc = wave * 2 + c;
      int r = cc * 16 + lrow16;
      long gb = (c0 + r) * (long)K + k0 + ((lg4 ^ ((lrow16 >> 1) & 3)) * 8);
      async16(Bh + gb, sBh + cc * 512);
      if constexpr (PASSES == 3) async16(Bl + gb, sBl + cc * 512);
    }
    __syncthreads();

    half8 ah[4], al[4], bh8[4], bl8[4];
    if constexpr (A32) {
#pragma unroll
      for (int mt = 0; mt < 4; ++mt) {
        int r = wm * 64 + mt * 16 + cl;
        int s0 = (quad * 2 + 0) ^ (r & 7), s1 = (quad * 2 + 1) ^ (r & 7);
        float fa[8];
        *(float4*)(fa) = *(const float4*)(sA32 + r * 32 + s0 * 4);
        *(float4*)(fa + 4) = *(const float4*)(sA32 + r * 32 + s1 * 4);
#pragma unroll
        for (int j = 0; j < 8; ++j) {
          _Float16 hh = (_Float16)fa[j];
          ah[mt][j] = hh;
          if constexpr (PASSES == 3) al[mt][j] = (_Float16)(fa[j] - (float)hh);
        }
      }
    } else {
#pragma unroll
      for (int mt = 0; mt < 4; ++mt) {
        int r = wm * 64 + mt * 16 + cl;
        int s = quad ^ ((r >> 1) & 3);
        ah[mt] = *(const half8*)(sA16 + r * 32 + s * 8);
      }
    }
#pragma unroll
    for (int nt = 0; nt < 4; ++nt) {
      int r = wn * 64 + nt * 16 + cl;
      int s = quad ^ ((r >> 1) & 3);
      bh8[nt] = *(const half8*)(sBh + r * 32 + s * 8);
      if constexpr (PASSES == 3) bl8[nt] = *(const half8*)(sBl + r * 32 + s * 8);
    }
#pragma unroll
    for (int mt = 0; mt < 4; ++mt)
#pragma unroll
      for (int nt = 0; nt < 4; ++nt) {
        acc[mt][nt] = __builtin_amdgcn_mfma_f32_16x16x32_f16(ah[mt], bh8[nt], acc[mt][nt], 0, 0, 0);
        if constexpr (PASSES == 3) {
          acc[mt][nt] = __builtin_amdgcn_mfma_f32_16x16x32_f16(ah[mt], bl8[nt], acc[mt][nt], 0, 0, 0);
          acc[mt][nt] = __builtin_amdgcn_mfma_f32_16x16x32_f16(al[mt], bh8[nt], acc[mt][nt], 0, 0, 0);
        }
      }
  }

#pragma unroll
  for (int mt = 0; mt < 4; ++mt)
#pragma unroll
    for (int nt = 0; nt < 4; ++nt)
#pragma unroll
      for (int i = 0; i < 4; ++i) {
        long row = r0 + wm * 64 + mt * 16 + quad * 4 + i;
        long col = c0 + wn * 64 + nt * 16 + cl;
        float v = acc[mt][nt][i];
        if constexpr (OUTMODE == 2) {
          ((float*)C0)[row * N + col] = v;
        } else if constexpr (OUTMODE == 0) {
          ((unsigned short*)C0)[row * N + col] = h2b((_Float16)v);
        } else {
          _Float16 hh = (_Float16)v;
          ((unsigned short*)C0)[row * N + col] = h2b(hh);
          ((unsigned short*)C1)[row * N + col] = h2b((_Float16)(v - (float)hh));
        }
      }
}

// ---- flash attention --------------------------------------------------------
// 1024 blocks: one 128-row q-tile each. blockIdx = qt_rank*64 + (b*16+h) with
// qt = 15 - qt_rank -> heaviest blocks dispatch FIRST (load balance), and all
// q-tiles of one (b,h) share an XCD under round-robin %8 (K/V L2 locality).
// 4 blocks/CU resident (LDS 35KB, VGPR<=128) to hide the per-tile barriers.
__global__ __launch_bounds__(256, 4) void flash_kernel(
    const unsigned short* __restrict__ qh_g, const unsigned short* __restrict__ ql_g,
    const unsigned short* __restrict__ kh_g, const unsigned short* __restrict__ kl_g,
    const unsigned short* __restrict__ vp_g, unsigned short* __restrict__ out) {
  __shared__ unsigned short sKh[64 * 64];
  __shared__ unsigned short sKl[64 * 64];
  __shared__ unsigned int sVtU[64 * 34];    // V^T: [dh][k/2] dword-packed, stride 34
  __shared__ unsigned short sP[4][32 * 40]; // per-wave P chunk [32][40]

  const int tid = threadIdx.x, lane = tid & 63, wave = tid >> 6;
  const int quad = lane >> 4, cl = lane & 15;
  const int bh = blockIdx.x & 63;
  const int qt = 15 - (blockIdx.x >> 6);
  const int h = bh & 15;
  const int b = bh >> 4;
  const long rowbase = (long)b * cS;
  const int q0 = qt * 128;
  const int lrow8 = lane >> 3, lg8 = lane & 7;

  // Q fragments register-resident, pre-scaled by 1/8 (exact in fp16)
  half8 qh[2][2], ql[2][2];
  const _Float16 s8 = (_Float16)0.125f;
#pragma unroll
  for (int ks = 0; ks < 2; ++ks)
#pragma unroll
    for (int mt = 0; mt < 2; ++mt) {
      long r = rowbase + q0 + wave * 32 + mt * 16 + cl;
      long off = r * cD + h * 64 + ks * 32 + quad * 8;
      qh[ks][mt] = *(const half8*)(qh_g + off) * s8;
      ql[ks][mt] = *(const half8*)(ql_g + off) * s8;
    }

  f32x4 O[2][5]; // [..][4] accumulates softmax denominator (ones column)
  float mrow[2][4];
#pragma unroll
  for (int mt = 0; mt < 2; ++mt) {
#pragma unroll
    for (int dt = 0; dt < 5; ++dt) O[mt][dt] = f32x4{0.f, 0.f, 0.f, 0.f};
#pragma unroll
    for (int i = 0; i < 4; ++i) mrow[mt][i] = -1e30f;
  }

  half8 vone;
#pragma unroll
  for (int j = 0; j < 8; ++j) vone[j] = (cl == 0) ? (_Float16)1.0f : (_Float16)0.0f;

  auto tile = [&](int ki, bool MASK) {
    __syncthreads();
    // stage K hi/lo (64x64 f16) via global_load_lds, XOR-swizzled granules
#pragma unroll
    for (int c = 0; c < 2; ++c) {
      int cc = wave * 2 + c;
      int r = cc * 8 + lrow8;
      long g = (rowbase + ki * 64 + r) * (long)cD + h * 64 + ((lg8 ^ lrow8) * 8);
      async16(kh_g + g, sKh + cc * 512);
      async16(kl_g + g, sKl + cc * 512);
    }
    // stage V^T dword-packed: thread t handles rows {2r2,2r2+1}, cols dc..dc+7
    {
      int r2 = tid & 31, dc = (tid >> 5) * 8;
      const unsigned short* gv = vp_g + (rowbase + ki * 64 + 2 * r2) * (long)cD + h * 64 + dc;
      unsigned short a[8], bb[8];
      *(uint4*)a = *(const uint4*)gv;
      *(uint4*)bb = *(const uint4*)(gv + cD);
#pragma unroll
      for (int j = 0; j < 8; ++j)
        sVtU[(dc + j) * 34 + r2] = (unsigned int)a[j] | ((unsigned int)bb[j] << 16);
    }
    __syncthreads();

    // S = Q K^T (3-pass hi/lo), pre-scaled
    f32x4 sacc[2][4];
#pragma unroll
    for (int mt = 0; mt < 2; ++mt)
#pragma unroll
      for (int nt = 0; nt < 4; ++nt) sacc[mt][nt] = f32x4{0.f, 0.f, 0.f, 0.f};
#pragma unroll
    for (int ks = 0; ks < 2; ++ks) {
      half8 kh8[4], kl8[4];
#pragma unroll
      for (int nt = 0; nt < 4; ++nt) {
        int r = nt * 16 + cl;
        int off = r * 64 + (((ks * 4 + quad) ^ (r & 7)) * 8);
        kh8[nt] = *(const half8*)(sKh + off);
        kl8[nt] = *(const half8*)(sKl + off);
      }
#pragma unroll
      for (int mt = 0; mt < 2; ++mt)
#pragma unroll
        for (int nt = 0; nt < 4; ++nt) {
          sacc[mt][nt] = __builtin_amdgcn_mfma_f32_16x16x32_f16(qh[ks][mt], kh8[nt], sacc[mt][nt], 0, 0, 0);
          sacc[mt][nt] = __builtin_amdgcn_mfma_f32_16x16x32_f16(qh[ks][mt], kl8[nt], sacc[mt][nt], 0, 0, 0);
          sacc[mt][nt] = __builtin_amdgcn_mfma_f32_16x16x32_f16(ql[ks][mt], kh8[nt], sacc[mt][nt], 0, 0, 0);
        }
    }
    if (MASK) {
#pragma unroll
      for (int mt = 0; mt < 2; ++mt)
#pragma unroll
        for (int nt = 0; nt < 4; ++nt)
#pragma unroll
          for (int i = 0; i < 4; ++i) {
            int rg = q0 + wave * 32 + mt * 16 + quad * 4 + i;
            int cg = ki * 64 + nt * 16 + cl;
            if (cg > rg) sacc[mt][nt][i] = -1e30f;
          }
    }
    // online max (16-lane shuffle); ballot-skip alpha rescale
    float mnew[2][4];
    bool ch = false;
#pragma unroll
    for (int mt = 0; mt < 2; ++mt)
#pragma unroll
      for (int i = 0; i < 4; ++i) {
        float mx = fmaxf(fmaxf(sacc[mt][0][i], sacc[mt][1][i]),
                         fmaxf(sacc[mt][2][i], sacc[mt][3][i]));
#pragma unroll
        for (int d = 1; d < 16; d <<= 1) mx = fmaxf(mx, __shfl_xor(mx, d));
        ch |= (mx > mrow[mt][i]);
        mnew[mt][i] = fmaxf(mrow[mt][i], mx);
      }
    if (__ballot(ch)) {
#pragma unroll
      for (int mt = 0; mt < 2; ++mt)
#pragma unroll
        for (int i = 0; i < 4; ++i) {
          float a = __expf(mrow[mt][i] - mnew[mt][i]);
#pragma unroll
          for (int dt = 0; dt < 5; ++dt) O[mt][dt][i] *= a;
        }
    }
#pragma unroll
    for (int mt = 0; mt < 2; ++mt)
#pragma unroll
      for (int i = 0; i < 4; ++i) mrow[mt][i] = mnew[mt][i];

    // P = exp(S - m) -> fp16; PV (+ones column for denominator)
    unsigned short* sPw = sP[wave];
#pragma unroll
    for (int kc = 0; kc < 2; ++kc) {
#pragma unroll
      for (int mt = 0; mt < 2; ++mt)
#pragma unroll
        for (int ntl = 0; ntl < 2; ++ntl) {
          int nt = kc * 2 + ntl;
#pragma unroll
          for (int i = 0; i < 4; ++i) {
            float p = __expf(sacc[mt][nt][i] - mrow[mt][i]);
            sPw[(mt * 16 + quad * 4 + i) * 40 + ntl * 16 + cl] = h2b((_Float16)p);
          }
        }
      half8 pa[2], vb[4];
#pragma unroll
      for (int mt = 0; mt < 2; ++mt)
        pa[mt] = *(const half8*)(sPw + (mt * 16 + cl) * 40 + quad * 8);
#pragma unroll
      for (int dt = 0; dt < 4; ++dt) {
        int base = (dt * 16 + cl) * 34 + kc * 16 + quad * 4;
        union { uint4 u; half8 hh; } cvt;
        uint2 p0 = *(const uint2*)(sVtU + base);
        uint2 p1 = *(const uint2*)(sVtU + base + 2);
        cvt.u = uint4{p0.x, p0.y, p1.x, p1.y};
        vb[dt] = cvt.hh;
      }
#pragma unroll
      for (int mt = 0; mt < 2; ++mt) {
#pragma unroll
        for (int dt = 0; dt < 4; ++dt)
          O[mt][dt] = __builtin_amdgcn_mfma_f32_16x16x32_f16(pa[mt], vb[dt], O[mt][dt], 0, 0, 0);
        O[mt][4] = __builtin_amdgcn_mfma_f32_16x16x32_f16(pa[mt], vone, O[mt][4], 0, 0, 0);
      }
    }
  };

  const int full = 2 * qt;
  for (int ki = 0; ki < full; ++ki) tile(ki, false);
  tile(full, true);
  tile(full + 1, true);

  // epilogue: O / l (l = ones-column accumulator at cl==0), f16 out
  float lv[2][4];
#pragma unroll
  for (int mt = 0; mt < 2; ++mt)
#pragma unroll
    for (int i = 0; i < 4; ++i) lv[mt][i] = __shfl(O[mt][4][i], (lane & 48));
#pragma unroll
  for (int mt = 0; mt < 2; ++mt)
#pragma unroll
    for (int dt = 0; dt < 4; ++dt)
#pragma unroll
      for (int i = 0; i < 4; ++i) {
        long r = rowbase + q0 + wave * 32 + mt * 16 + quad * 4 + i;
        out[r * cD + h * 64 + dt * 16 + cl] = h2b((_Float16)(O[mt][dt][i] / lv[mt][i]));
      }
}

// ---------------------------------------------------------------------------
extern "C" void kernel_launch(void* const* d_in, const int* in_sizes, int n_in,
                              void* d_out, int out_size, void* d_ws, size_t ws_size,
                              hipStream_t stream) {
  const float* Q = (const float*)d_in[0];
  const float* K = (const float*)d_in[1];
  const float* V = (const float*)d_in[2];
  const float* Wq = (const float*)d_in[3];
  const float* Wk = (const float*)d_in[4];
  const float* Wv = (const float*)d_in[5];
  const float* Wo = (const float*)d_in[6];

  unsigned short* ws = (unsigned short*)d_ws;
  const size_t WD = (size_t)cD * cD;
  const size_t WM = (size_t)cM * cD;
  unsigned short* Wqh = ws;
  unsigned short* Wql = Wqh + WD;
  unsigned short* Wkh = Wql + WD;
  unsigned short* Wkl = Wkh + WD;
  unsigned short* Wvh = Wkl + WD;
  unsigned short* Woh = Wvh + WD;
  unsigned short* qph = Woh + WD;
  unsigned short* qpl = qph + WM;
  unsigned short* kph = qpl + WM;
  unsigned short* kpl = kph + WM;
  unsigned short* vp = kpl + WM;
  unsigned short* attnb = vp + WM;

  const int nW = (int)WD;
  split_f16_kernel<<<nW / 1024, 256, 0, stream>>>(Wq, Wqh, Wql, nW);
  split_f16_kernel<<<nW / 1024, 256, 0, stream>>>(Wk, Wkh, Wkl, nW);
  split_f16_kernel<<<nW / 1024, 256, 0, stream>>>(Wv, Wvh, nullptr, nW);
  split_f16_kernel<<<nW / 1024, 256, 0, stream>>>(Wo, Woh, nullptr, nW);

  const int gblk = (cM / 128) * (cD / 128); // 512
  gemm_bt<3, 1, true><<<gblk, 256, 0, stream>>>(Q, Wqh, Wql, qph, qpl, cM, cD, cD);
  gemm_bt<3, 1, true><<<gblk, 256, 0, stream>>>(K, Wkh, Wkl, kph, kpl, cM, cD, cD);
  gemm_bt<1, 0, true><<<gblk, 256, 0, stream>>>(V, Wvh, nullptr, vp, nullptr, cM, cD, cD);

  flash_kernel<<<cB * cH * 16, 256, 0, stream>>>(qph, qpl, kph, kpl, vp, attnb);

  gemm_bt<1, 2, false><<<gblk, 256, 0, stream>>>(attnb, Woh, nullptr, d_out, nullptr, cM, cD, cD);
}

// Round 5
// 501.628 us; speedup vs baseline: 1.2101x; 1.2101x over previous
//
#include <hip/hip_runtime.h>

// ---------------------------------------------------------------------------
// casual MHA, MI355X. fp32 in/out, fp16 MFMA compute.
// q/k path uses 2-term fp16 split (hi+lo, 3 MFMA passes) to keep softmax
// logits (std ~1024) accurate enough that argmax-like softmax doesn't flip.
// ---------------------------------------------------------------------------

typedef __attribute__((ext_vector_type(8))) _Float16 half8;
typedef __attribute__((ext_vector_type(4))) float f32x4;

#define DEVI static __device__ __forceinline__

static constexpr int cB = 4, cS = 2048, cD = 1024, cH = 16, cDH = 64;
static constexpr int cM = cB * cS; // 8192

DEVI unsigned short h2b(_Float16 h) { union { _Float16 f; unsigned short u; } x; x.f = h; return x.u; }

DEVI void async16(const void* g, void* l) {
#if defined(__HIP_DEVICE_COMPILE__)
  __builtin_amdgcn_global_load_lds((const __attribute__((address_space(1))) unsigned int*)g,
                                   (__attribute__((address_space(3))) unsigned int*)l, 16, 0, 0);
#endif
}

// ---- split fp32 -> fp16 hi (+lo) --------------------------------------------
__global__ void split_f16_kernel(const float* __restrict__ in, unsigned short* __restrict__ hi,
                                 unsigned short* __restrict__ lo, int n) {
  int i = (blockIdx.x * blockDim.x + threadIdx.x) * 4;
  if (i >= n) return;
  float4 v = *(const float4*)(in + i);
  _Float16 h0 = (_Float16)v.x, h1 = (_Float16)v.y, h2 = (_Float16)v.z, h3 = (_Float16)v.w;
  unsigned short th[4] = {h2b(h0), h2b(h1), h2b(h2), h2b(h3)};
  *(uint2*)(hi + i) = *(const uint2*)th;
  if (lo != nullptr) {
    unsigned short tl[4] = {h2b((_Float16)(v.x - (float)h0)), h2b((_Float16)(v.y - (float)h1)),
                            h2b((_Float16)(v.z - (float)h2)), h2b((_Float16)(v.w - (float)h3))};
    *(uint2*)(lo + i) = *(const uint2*)tl;
  }
}

// ---- GEMM: C[M,N] = A[M,K] @ B[N,K]^T --------------------------------------
template <int PASSES, int OUTMODE, bool A32>
__global__ __launch_bounds__(256, 2) void gemm_bt(const void* __restrict__ Ap,
                                                  const unsigned short* __restrict__ Bh,
                                                  const unsigned short* __restrict__ Bl,
                                                  void* __restrict__ C0, void* __restrict__ C1,
                                                  int M, int N, int K) {
  __shared__ float sA32[A32 ? 128 * 32 : 1];
  __shared__ unsigned short sA16[A32 ? 1 : 128 * 32];
  __shared__ unsigned short sBh[128 * 32];
  __shared__ unsigned short sBl[(PASSES == 3) ? 128 * 32 : 1];

  const int tid = threadIdx.x, lane = tid & 63, wave = tid >> 6;
  const int wm = wave >> 1, wn = wave & 1;
  const int nb = N >> 7;
  const int bm = blockIdx.x / nb, bn = blockIdx.x % nb;
  const long r0 = (long)bm * 128, c0 = (long)bn * 128;
  const int quad = lane >> 4, cl = lane & 15;

  f32x4 acc[4][4];
#pragma unroll
  for (int mt = 0; mt < 4; ++mt)
#pragma unroll
    for (int nt = 0; nt < 4; ++nt) acc[mt][nt] = f32x4{0.f, 0.f, 0.f, 0.f};

  const int lrow8 = lane >> 3, lg8 = lane & 7;
  const int lrow16 = lane >> 2, lg4 = lane & 3;

  const float* A32p = (const float*)Ap;
  const unsigned short* A16p = (const unsigned short*)Ap;

  for (int k0 = 0; k0 < K; k0 += 32) {
    __syncthreads();
    if constexpr (A32) {
#pragma unroll
      for (int c = 0; c < 4; ++c) {
        int cc = wave * 4 + c;
        int r = cc * 8 + lrow8;
        const float* g = A32p + (r0 + r) * (long)K + k0 + ((lg8 ^ lrow8) * 4);
        async16(g, sA32 + cc * 256);
      }
    } else {
#pragma unroll
      for (int c = 0; c < 2; ++c) {
        int cc = wave * 2 + c;
        int r = cc * 16 + lrow16;
        const unsigned short* g =
            A16p + (r0 + r) * (long)K + k0 + ((lg4 ^ ((lrow16 >> 1) & 3)) * 8);
        async16(g, sA16 + cc * 512);
      }
    }
#pragma unroll
    for (int c = 0; c < 2; ++c) {
      int cc = wave * 2 + c;
      int r = cc * 16 + lrow16;
      long gb = (c0 + r) * (long)K + k0 + ((lg4 ^ ((lrow16 >> 1) & 3)) * 8);
      async16(Bh + gb, sBh + cc * 512);
      if constexpr (PASSES == 3) async16(Bl + gb, sBl + cc * 512);
    }
    __syncthreads();

    half8 ah[4], al[4], bh8[4], bl8[4];
    if constexpr (A32) {
#pragma unroll
      for (int mt = 0; mt < 4; ++mt) {
        int r = wm * 64 + mt * 16 + cl;
        int s0 = (quad * 2 + 0) ^ (r & 7), s1 = (quad * 2 + 1) ^ (r & 7);
        float fa[8];
        *(float4*)(fa) = *(const float4*)(sA32 + r * 32 + s0 * 4);
        *(float4*)(fa + 4) = *(const float4*)(sA32 + r * 32 + s1 * 4);
#pragma unroll
        for (int j = 0; j < 8; ++j) {
          _Float16 hh = (_Float16)fa[j];
          ah[mt][j] = hh;
          if constexpr (PASSES == 3) al[mt][j] = (_Float16)(fa[j] - (float)hh);
        }
      }
    } else {
#pragma unroll
      for (int mt = 0; mt < 4; ++mt) {
        int r = wm * 64 + mt * 16 + cl;
        int s = quad ^ ((r >> 1) & 3);
        ah[mt] = *(const half8*)(sA16 + r * 32 + s * 8);
      }
    }
#pragma unroll
    for (int nt = 0; nt < 4; ++nt) {
      int r = wn * 64 + nt * 16 + cl;
      int s = quad ^ ((r >> 1) & 3);
      bh8[nt] = *(const half8*)(sBh + r * 32 + s * 8);
      if constexpr (PASSES == 3) bl8[nt] = *(const half8*)(sBl + r * 32 + s * 8);
    }
#pragma unroll
    for (int mt = 0; mt < 4; ++mt)
#pragma unroll
      for (int nt = 0; nt < 4; ++nt) {
        acc[mt][nt] = __builtin_amdgcn_mfma_f32_16x16x32_f16(ah[mt], bh8[nt], acc[mt][nt], 0, 0, 0);
        if constexpr (PASSES == 3) {
          acc[mt][nt] = __builtin_amdgcn_mfma_f32_16x16x32_f16(ah[mt], bl8[nt], acc[mt][nt], 0, 0, 0);
          acc[mt][nt] = __builtin_amdgcn_mfma_f32_16x16x32_f16(al[mt], bh8[nt], acc[mt][nt], 0, 0, 0);
        }
      }
  }

#pragma unroll
  for (int mt = 0; mt < 4; ++mt)
#pragma unroll
    for (int nt = 0; nt < 4; ++nt)
#pragma unroll
      for (int i = 0; i < 4; ++i) {
        long row = r0 + wm * 64 + mt * 16 + quad * 4 + i;
        long col = c0 + wn * 64 + nt * 16 + cl;
        float v = acc[mt][nt][i];
        if constexpr (OUTMODE == 2) {
          ((float*)C0)[row * N + col] = v;
        } else if constexpr (OUTMODE == 0) {
          ((unsigned short*)C0)[row * N + col] = h2b((_Float16)v);
        } else {
          _Float16 hh = (_Float16)v;
          ((unsigned short*)C0)[row * N + col] = h2b(hh);
          ((unsigned short*)C1)[row * N + col] = h2b((_Float16)(v - (float)hh));
        }
      }
}

// ---- flash attention --------------------------------------------------------
// 1024 blocks: one 128-row q-tile each. blockIdx = qt_rank*64 + (b*16+h) with
// qt = 15 - qt_rank -> heaviest blocks dispatch FIRST (load balance), and all
// q-tiles of one (b,h) share an XCD under round-robin %8 (K/V L2 locality).
// __launch_bounds__(256,3): VGPR budget ~170 -> allocator lands ~84, NO spill
// (256,4 squeezed to 64 VGPR -> scratch spill -> +500MB HBM traffic, regressed).
// Co-residency (4 blocks/CU) comes from the grid size + 35KB LDS, not bounds.
__global__ __launch_bounds__(256, 3) void flash_kernel(
    const unsigned short* __restrict__ qh_g, const unsigned short* __restrict__ ql_g,
    const unsigned short* __restrict__ kh_g, const unsigned short* __restrict__ kl_g,
    const unsigned short* __restrict__ vp_g, unsigned short* __restrict__ out) {
  __shared__ unsigned short sKh[64 * 64];
  __shared__ unsigned short sKl[64 * 64];
  __shared__ unsigned int sVtU[64 * 34];    // V^T: [dh][k/2] dword-packed, stride 34
  __shared__ unsigned short sP[4][32 * 40]; // per-wave P chunk [32][40]

  const int tid = threadIdx.x, lane = tid & 63, wave = tid >> 6;
  const int quad = lane >> 4, cl = lane & 15;
  const int bh = blockIdx.x & 63;
  const int qt = 15 - (blockIdx.x >> 6);
  const int h = bh & 15;
  const int b = bh >> 4;
  const long rowbase = (long)b * cS;
  const int q0 = qt * 128;
  const int lrow8 = lane >> 3, lg8 = lane & 7;

  // Q fragments register-resident, pre-scaled by 1/8 (exact in fp16)
  half8 qh[2][2], ql[2][2];
  const _Float16 s8 = (_Float16)0.125f;
#pragma unroll
  for (int ks = 0; ks < 2; ++ks)
#pragma unroll
    for (int mt = 0; mt < 2; ++mt) {
      long r = rowbase + q0 + wave * 32 + mt * 16 + cl;
      long off = r * cD + h * 64 + ks * 32 + quad * 8;
      qh[ks][mt] = *(const half8*)(qh_g + off) * s8;
      ql[ks][mt] = *(const half8*)(ql_g + off) * s8;
    }

  f32x4 O[2][5]; // [..][4] accumulates softmax denominator (ones column)
  float mrow[2][4];
#pragma unroll
  for (int mt = 0; mt < 2; ++mt) {
#pragma unroll
    for (int dt = 0; dt < 5; ++dt) O[mt][dt] = f32x4{0.f, 0.f, 0.f, 0.f};
#pragma unroll
    for (int i = 0; i < 4; ++i) mrow[mt][i] = -1e30f;
  }

  half8 vone;
#pragma unroll
  for (int j = 0; j < 8; ++j) vone[j] = (cl == 0) ? (_Float16)1.0f : (_Float16)0.0f;

  auto tile = [&](int ki, bool MASK) {
    __syncthreads();
    // stage K hi/lo (64x64 f16) via global_load_lds, XOR-swizzled granules
#pragma unroll
    for (int c = 0; c < 2; ++c) {
      int cc = wave * 2 + c;
      int r = cc * 8 + lrow8;
      long g = (rowbase + ki * 64 + r) * (long)cD + h * 64 + ((lg8 ^ lrow8) * 8);
      async16(kh_g + g, sKh + cc * 512);
      async16(kl_g + g, sKl + cc * 512);
    }
    // stage V^T dword-packed: thread t handles rows {2r2,2r2+1}, cols dc..dc+7
    {
      int r2 = tid & 31, dc = (tid >> 5) * 8;
      const unsigned short* gv = vp_g + (rowbase + ki * 64 + 2 * r2) * (long)cD + h * 64 + dc;
      unsigned short a[8], bb[8];
      *(uint4*)a = *(const uint4*)gv;
      *(uint4*)bb = *(const uint4*)(gv + cD);
#pragma unroll
      for (int j = 0; j < 8; ++j)
        sVtU[(dc + j) * 34 + r2] = (unsigned int)a[j] | ((unsigned int)bb[j] << 16);
    }
    __syncthreads();

    // S = Q K^T (3-pass hi/lo), pre-scaled
    f32x4 sacc[2][4];
#pragma unroll
    for (int mt = 0; mt < 2; ++mt)
#pragma unroll
      for (int nt = 0; nt < 4; ++nt) sacc[mt][nt] = f32x4{0.f, 0.f, 0.f, 0.f};
#pragma unroll
    for (int ks = 0; ks < 2; ++ks) {
      half8 kh8[4], kl8[4];
#pragma unroll
      for (int nt = 0; nt < 4; ++nt) {
        int r = nt * 16 + cl;
        int off = r * 64 + (((ks * 4 + quad) ^ (r & 7)) * 8);
        kh8[nt] = *(const half8*)(sKh + off);
        kl8[nt] = *(const half8*)(sKl + off);
      }
#pragma unroll
      for (int mt = 0; mt < 2; ++mt)
#pragma unroll
        for (int nt = 0; nt < 4; ++nt) {
          sacc[mt][nt] = __builtin_amdgcn_mfma_f32_16x16x32_f16(qh[ks][mt], kh8[nt], sacc[mt][nt], 0, 0, 0);
          sacc[mt][nt] = __builtin_amdgcn_mfma_f32_16x16x32_f16(qh[ks][mt], kl8[nt], sacc[mt][nt], 0, 0, 0);
          sacc[mt][nt] = __builtin_amdgcn_mfma_f32_16x16x32_f16(ql[ks][mt], kh8[nt], sacc[mt][nt], 0, 0, 0);
        }
    }
    if (MASK) {
#pragma unroll
      for (int mt = 0; mt < 2; ++mt)
#pragma unroll
        for (int nt = 0; nt < 4; ++nt)
#pragma unroll
          for (int i = 0; i < 4; ++i) {
            int rg = q0 + wave * 32 + mt * 16 + quad * 4 + i;
            int cg = ki * 64 + nt * 16 + cl;
            if (cg > rg) sacc[mt][nt][i] = -1e30f;
          }
    }
    // online max (16-lane shuffle); ballot-skip alpha rescale
    float mnew[2][4];
    bool ch = false;
#pragma unroll
    for (int mt = 0; mt < 2; ++mt)
#pragma unroll
      for (int i = 0; i < 4; ++i) {
        float mx = fmaxf(fmaxf(sacc[mt][0][i], sacc[mt][1][i]),
                         fmaxf(sacc[mt][2][i], sacc[mt][3][i]));
#pragma unroll
        for (int d = 1; d < 16; d <<= 1) mx = fmaxf(mx, __shfl_xor(mx, d));
        ch |= (mx > mrow[mt][i]);
        mnew[mt][i] = fmaxf(mrow[mt][i], mx);
      }
    if (__ballot(ch)) {
#pragma unroll
      for (int mt = 0; mt < 2; ++mt)
#pragma unroll
        for (int i = 0; i < 4; ++i) {
          float a = __expf(mrow[mt][i] - mnew[mt][i]);
#pragma unroll
          for (int dt = 0; dt < 5; ++dt) O[mt][dt][i] *= a;
        }
    }
#pragma unroll
    for (int mt = 0; mt < 2; ++mt)
#pragma unroll
      for (int i = 0; i < 4; ++i) mrow[mt][i] = mnew[mt][i];

    // P = exp(S - m) -> fp16; PV (+ones column for denominator)
    unsigned short* sPw = sP[wave];
#pragma unroll
    for (int kc = 0; kc < 2; ++kc) {
#pragma unroll
      for (int mt = 0; mt < 2; ++mt)
#pragma unroll
        for (int ntl = 0; ntl < 2; ++ntl) {
          int nt = kc * 2 + ntl;
#pragma unroll
          for (int i = 0; i < 4; ++i) {
            float p = __expf(sacc[mt][nt][i] - mrow[mt][i]);
            sPw[(mt * 16 + quad * 4 + i) * 40 + ntl * 16 + cl] = h2b((_Float16)p);
          }
        }
      half8 pa[2], vb[4];
#pragma unroll
      for (int mt = 0; mt < 2; ++mt)
        pa[mt] = *(const half8*)(sPw + (mt * 16 + cl) * 40 + quad * 8);
#pragma unroll
      for (int dt = 0; dt < 4; ++dt) {
        int base = (dt * 16 + cl) * 34 + kc * 16 + quad * 4;
        union { uint4 u; half8 hh; } cvt;
        uint2 p0 = *(const uint2*)(sVtU + base);
        uint2 p1 = *(const uint2*)(sVtU + base + 2);
        cvt.u = uint4{p0.x, p0.y, p1.x, p1.y};
        vb[dt] = cvt.hh;
      }
#pragma unroll
      for (int mt = 0; mt < 2; ++mt) {
#pragma unroll
        for (int dt = 0; dt < 4; ++dt)
          O[mt][dt] = __builtin_amdgcn_mfma_f32_16x16x32_f16(pa[mt], vb[dt], O[mt][dt], 0, 0, 0);
        O[mt][4] = __builtin_amdgcn_mfma_f32_16x16x32_f16(pa[mt], vone, O[mt][4], 0, 0, 0);
      }
    }
  };

  const int full = 2 * qt;
  for (int ki = 0; ki < full; ++ki) tile(ki, false);
  tile(full, true);
  tile(full + 1, true);

  // epilogue: O / l (l = ones-column accumulator at cl==0), f16 out
  float lv[2][4];
#pragma unroll
  for (int mt = 0; mt < 2; ++mt)
#pragma unroll
    for (int i = 0; i < 4; ++i) lv[mt][i] = __shfl(O[mt][4][i], (lane & 48));
#pragma unroll
  for (int mt = 0; mt < 2; ++mt)
#pragma unroll
    for (int dt = 0; dt < 4; ++dt)
#pragma unroll
      for (int i = 0; i < 4; ++i) {
        long r = rowbase + q0 + wave * 32 + mt * 16 + quad * 4 + i;
        out[r * cD + h * 64 + dt * 16 + cl] = h2b((_Float16)(O[mt][dt][i] / lv[mt][i]));
      }
}

// ---------------------------------------------------------------------------
extern "C" void kernel_launch(void* const* d_in, const int* in_sizes, int n_in,
                              void* d_out, int out_size, void* d_ws, size_t ws_size,
                              hipStream_t stream) {
  const float* Q = (const float*)d_in[0];
  const float* K = (const float*)d_in[1];
  const float* V = (const float*)d_in[2];
  const float* Wq = (const float*)d_in[3];
  const float* Wk = (const float*)d_in[4];
  const float* Wv = (const float*)d_in[5];
  const float* Wo = (const float*)d_in[6];

  unsigned short* ws = (unsigned short*)d_ws;
  const size_t WD = (size_t)cD * cD;
  const size_t WM = (size_t)cM * cD;
  unsigned short* Wqh = ws;
  unsigned short* Wql = Wqh + WD;
  unsigned short* Wkh = Wql + WD;
  unsigned short* Wkl = Wkh + WD;
  unsigned short* Wvh = Wkl + WD;
  unsigned short* Woh = Wvh + WD;
  unsigned short* qph = Woh + WD;
  unsigned short* qpl = qph + WM;
  unsigned short* kph = qpl + WM;
  unsigned short* kpl = kph + WM;
  unsigned short* vp = kpl + WM;
  unsigned short* attnb = vp + WM;

  const int nW = (int)WD;
  split_f16_kernel<<<nW / 1024, 256, 0, stream>>>(Wq, Wqh, Wql, nW);
  split_f16_kernel<<<nW / 1024, 256, 0, stream>>>(Wk, Wkh, Wkl, nW);
  split_f16_kernel<<<nW / 1024, 256, 0, stream>>>(Wv, Wvh, nullptr, nW);
  split_f16_kernel<<<nW / 1024, 256, 0, stream>>>(Wo, Woh, nullptr, nW);

  const int gblk = (cM / 128) * (cD / 128); // 512
  gemm_bt<3, 1, true><<<gblk, 256, 0, stream>>>(Q, Wqh, Wql, qph, qpl, cM, cD, cD);
  gemm_bt<3, 1, true><<<gblk, 256, 0, stream>>>(K, Wkh, Wkl, kph, kpl, cM, cD, cD);
  gemm_bt<1, 0, true><<<gblk, 256, 0, stream>>>(V, Wvh, nullptr, vp, nullptr, cM, cD, cD);

  flash_kernel<<<cB * cH * 16, 256, 0, stream>>>(qph, qpl, kph, kpl, vp, attnb);

  gemm_bt<1, 2, false><<<gblk, 256, 0, stream>>>(attnb, Woh, nullptr, d_out, nullptr, cM, cD, cD);
}